// Round 6
// baseline (50.728 us; speedup 1.0000x reference)
//
#include <hip/hip_runtime.h>
#include <stdint.h>

// loss = sum_{b,m,n} | dot(src[b,n,:], tgts[b,m,n,:]) |
// B=64, M=16, N=64, D=1024
//
// DMA-streaming (T3/T4): one wave per (b, n, m-half), all fetches via
// global_load_lds with hand-counted s_waitcnt vmcnt(8) (never drains to 0 in
// steady state). R6 change vs R5: src row is staged through RING SLOT 2
// instead of a dedicated srcb buffer -> LDS/block 64 KiB -> 48 KiB ->
// 3 blocks/CU (12 waves/CU instead of 8).

typedef __attribute__((ext_vector_type(4))) float f32x4;
typedef const __attribute__((address_space(1))) void* gvp;
typedef __attribute__((address_space(3))) void* svp;

#define GLDS(gp, lp) \
  __builtin_amdgcn_global_load_lds((gvp)(gp), (svp)(lp), 16, 0, 0)

#define WAITV(n) asm volatile("s_waitcnt vmcnt(" #n ")" ::: "memory")
#define CFENCE() asm volatile("" ::: "memory")

__global__ __launch_bounds__(256) void orth_loss_main(
    const float* __restrict__ src,
    const float* __restrict__ tgts,
    float* __restrict__ partials)
{
    __shared__ float ring[4][3][1024];   // 4 waves x 3 row-buffers x 4 KiB
    __shared__ float sbuf[4];

    const int wave = threadIdx.x >> 6;   // 0..3
    const int lane = threadIdx.x & 63;

    const int w  = blockIdx.x * 4 + wave;   // 0..8191, exact grid
    const int n  = w & 63;                  // N = 64
    const int t  = w >> 6;
    const int mh = t & 1;                   // m-half: rows m = mh*8 + 0..7
    const int b  = t >> 1;

    const float* srow = src + ((size_t)(b * 64 + n)) * 1024 + lane * 4;
    const int    base_row = (b * 16 + mh * 8) * 64 + n;
    const float* trow = tgts + (size_t)base_row * 1024 + lane * 4;
    const size_t mstride = (size_t)64 * 1024;   // floats between m-rows

    // ---- prologue: src -> ring[2], row0 -> ring[0], row1 -> ring[1] ----
#pragma unroll
    for (int k = 0; k < 4; ++k)
        GLDS(srow + k * 256, &ring[wave][2][k * 256]);
#pragma unroll
    for (int r = 0; r < 2; ++r) {
#pragma unroll
        for (int k = 0; k < 4; ++k)
            GLDS(trow + r * mstride + k * 256, &ring[wave][r][k * 256]);
    }

    // pre-step: wait for src (oldest 4 of 12), pull to regs, issue row2
    WAITV(8);
    f32x4 s0, s1, s2, s3;
    {
        const f32x4* sb_ = (const f32x4*)&ring[wave][2][0];
        s0 = sb_[lane];       s1 = sb_[lane + 64];
        s2 = sb_[lane + 128]; s3 = sb_[lane + 192];
    }
    CFENCE();   // ds_reads of src stay above the overwrite of ring[2]
    asm volatile("s_waitcnt lgkmcnt(0)" ::: "memory");  // src regs live
    CFENCE();
#pragma unroll
    for (int k = 0; k < 4; ++k)
        GLDS(trow + 2 * mstride + k * 256, &ring[wave][2][k * 256]);

    float local = 0.0f;

    // steps 0..7: wait vmcnt(8) (oldest row done, 2 rows in flight),
    // compute from ring[i%3], reuse that slot for row i+3. Tail: 8 -> 4 -> 0.
#define STEP(MI, DO_ISSUE, WN) do {                                          \
      WAITV(WN);                                                             \
      const f32x4* lb_ = (const f32x4*)&ring[wave][(MI) % 3][0];             \
      const f32x4 t0 = lb_[lane];                                            \
      const f32x4 t1 = lb_[lane + 64];                                       \
      const f32x4 t2 = lb_[lane + 128];                                      \
      const f32x4 t3 = lb_[lane + 192];                                      \
      float dot = 0.0f;                                                      \
      dot = fmaf(t0.x, s0.x, dot); dot = fmaf(t0.y, s0.y, dot);              \
      dot = fmaf(t0.z, s0.z, dot); dot = fmaf(t0.w, s0.w, dot);              \
      dot = fmaf(t1.x, s1.x, dot); dot = fmaf(t1.y, s1.y, dot);              \
      dot = fmaf(t1.z, s1.z, dot); dot = fmaf(t1.w, s1.w, dot);              \
      dot = fmaf(t2.x, s2.x, dot); dot = fmaf(t2.y, s2.y, dot);              \
      dot = fmaf(t2.z, s2.z, dot); dot = fmaf(t2.w, s2.w, dot);              \
      dot = fmaf(t3.x, s3.x, dot); dot = fmaf(t3.y, s3.y, dot);              \
      dot = fmaf(t3.z, s3.z, dot); dot = fmaf(t3.w, s3.w, dot);              \
      _Pragma("unroll")                                                      \
      for (int off = 32; off > 0; off >>= 1)                                 \
          dot += __shfl_down(dot, off, 64);                                  \
      if (lane == 0) local += fabsf(dot);                                    \
      CFENCE(); /* LDS reads above, next GLDS below */                       \
      if (DO_ISSUE) {                                                        \
        _Pragma("unroll")                                                    \
        for (int k = 0; k < 4; ++k)                                          \
            GLDS(trow + ((MI) + 3) * mstride + k * 256,                      \
                 &ring[wave][(MI) % 3][k * 256]);                            \
      }                                                                      \
    } while (0)

    STEP(0, 1, 8);
    STEP(1, 1, 8);
    STEP(2, 1, 8);
    STEP(3, 1, 8);
    STEP(4, 1, 8);
    STEP(5, 0, 8);
    STEP(6, 0, 4);
    STEP(7, 0, 0);
#undef STEP

    if (lane == 0) sbuf[wave] = local;
    __syncthreads();
    if (threadIdx.x == 0)
        partials[blockIdx.x] = sbuf[0] + sbuf[1] + sbuf[2] + sbuf[3];
}

__global__ __launch_bounds__(256) void reduce_partials(
    const float* __restrict__ partials, float* __restrict__ out, int n)
{
    __shared__ float sb[4];
    const int lane = threadIdx.x & 63;
    const int wv   = threadIdx.x >> 6;
    float s = 0.0f;
    for (int i = threadIdx.x; i < n; i += 256) s += partials[i];
#pragma unroll
    for (int off = 32; off > 0; off >>= 1) s += __shfl_down(s, off, 64);
    if (lane == 0) sb[wv] = s;
    __syncthreads();
    if (threadIdx.x == 0) out[0] = sb[0] + sb[1] + sb[2] + sb[3];
}

extern "C" void kernel_launch(void* const* d_in, const int* in_sizes, int n_in,
                              void* d_out, int out_size, void* d_ws, size_t ws_size,
                              hipStream_t stream) {
    const float* src  = (const float*)d_in[0];   // [B, N, D]
    const float* tgts = (const float*)d_in[1];   // [B, M, N, D]
    float* out      = (float*)d_out;             // [1]
    float* partials = (float*)d_ws;              // 2048 floats

    // one wave per (b, n, m-half): B*N*2 waves, 4 waves/block
    const int total_waves = (in_sizes[0] / 1024) * 2;   // 8192
    const int blocks = total_waves / 4;                  // 2048

    orth_loss_main<<<blocks, 256, 0, stream>>>(src, tgts, partials);
    reduce_partials<<<1, 256, 0, stream>>>(partials, out, blocks);
}